// Round 14
// baseline (191.980 us; speedup 1.0000x reference)
//
#include <hip/hip_runtime.h>
#include <hip/hip_bf16.h>

#define B_ 4
#define M_ 5
#define N_ 1000
#define FIN 64
#define H_ 4
#define D_ 64
#define HD 256
#define SH 128
#define OUTD 5
#define NW 16  // u64 words per dest row (1024/64)
#define THRESH_ 0.97f

typedef unsigned short u16;
typedef u16 us8 __attribute__((ext_vector_type(8)));
typedef short s16x8 __attribute__((ext_vector_type(8)));
typedef float f32x4 __attribute__((ext_vector_type(4)));

__device__ inline u16 bf16_bits(float v) {
  __hip_bfloat16 h = __float2bfloat16(v);
  return *reinterpret_cast<u16*>(&h);
}
__device__ inline float bf16_val(u16 b) {
  __hip_bfloat16 h;
  *reinterpret_cast<u16*>(&h) = b;
  return __bfloat162float(h);
}
__device__ inline float b2f(u16 u) {
  union { unsigned int i; float f; } c;
  c.i = ((unsigned int)u) << 16;
  return c.f;
}
__device__ inline void split2(float v, u16& h, u16& l) {
  h = bf16_bits(v);
  l = bf16_bits(v - bf16_val(h));
}
__device__ inline void beta_from_sums(const float* __restrict__ psum,
                                      const int* __restrict__ node_nums,
                                      float* bb) {
  float tot = (float)(node_nums[0] + node_nums[1] + node_nums[2] + node_nums[3]);
  float w[M_], mx = -1e30f;
#pragma unroll
  for (int m = 0; m < M_; ++m) {
    w[m] = psum[m] / tot;
    mx = fmaxf(mx, w[m]);
  }
  float s = 0.f;
#pragma unroll
  for (int m = 0; m < M_; ++m) {
    w[m] = __expf(w[m] - mx);
    s += w[m];
  }
  float inv = 1.f / s;
#pragma unroll
  for (int m = 0; m < M_; ++m) bb[m] = w[m] * inv;
}

// ---------------------------------------------------------------------------
// prep_all: bit-packed transposed edge mask + all weight transpose/split jobs.
// ---------------------------------------------------------------------------
__device__ void splitT_body(const float* __restrict__ s, u16* __restrict__ hiT,
                            u16* __restrict__ loT, int K, int N, int k0, int n0,
                            char* smem) {
  float(*tile)[33] = (float(*)[33])smem;
  int tid = threadIdx.x;
  int kl = tid >> 3, nq = (tid & 7) * 4;
  *(float4*)&tile[kl][nq] = *(const float4*)(s + (size_t)(k0 + kl) * N + n0 + nq);
  __syncthreads();
  int nl = tid >> 3, kq = (tid & 7) * 4;
  ushort4 h, l;
  split2(tile[kq + 0][nl], h.x, l.x);
  split2(tile[kq + 1][nl], h.y, l.y);
  split2(tile[kq + 2][nl], h.z, l.z);
  split2(tile[kq + 3][nl], h.w, l.w);
  size_t o = (size_t)(n0 + nl) * K + k0 + kq;
  *(ushort4*)(hiT + o) = h;
  *(ushort4*)(loT + o) = l;
}

__global__ __launch_bounds__(256) void prep_all(
    const float* __restrict__ adj, const int* __restrict__ node_nums,
    unsigned long long* __restrict__ maskW,
    const float* __restrict__ fc1, u16* __restrict__ fc1Th, u16* __restrict__ fc1Tl,
    const float* __restrict__ fc2, u16* __restrict__ fc2Th, u16* __restrict__ fc2Tl,
    const float* __restrict__ sW1_1, u16* __restrict__ sW1Th1, u16* __restrict__ sW1Tl1,
    const float* __restrict__ sW1_2, u16* __restrict__ sW1Th2, u16* __restrict__ sW1Tl2) {
  __shared__ __align__(16) char smem[4608];
  int bi = blockIdx.x;
  int tid = threadIdx.x;
  if (bi < 5120) {
    int bx = bi & 15, by = (bi >> 4) & 15, bm = bi >> 8;
    int b = bm / M_;
    int s0 = bx * 64, d0 = by * 64;
    int nn = node_nums[b];
    unsigned char(*tile)[65] = (unsigned char(*)[65])smem;
    const float* arow = adj + (size_t)bm * N_ * N_;
#pragma unroll
    for (int k = 0; k < 16; ++k) {
      int idx = k * 256 + tid;
      int sl = idx >> 6, dl = idx & 63;
      int s = s0 + sl, d = d0 + dl;
      unsigned char v = 0;
      if (s < nn && d < nn && s < N_ && d < N_)
        v = (arow[(size_t)s * N_ + d] > THRESH_) ? 1 : 0;
      tile[sl][dl] = v;
    }
    __syncthreads();
    int w = tid >> 6, lane = tid & 63;
#pragma unroll
    for (int j = 0; j < 16; ++j) {
      int dl = w * 16 + j;
      bool act = tile[lane][dl] != 0;
      unsigned long long word = __ballot(act);
      int d = d0 + dl;
      if (lane == 0 && d < N_)
        maskW[((size_t)bm * N_ + d) * NW + bx] = word;
    }
    return;
  }
  bi -= 5120;
  if (bi < 80) {
    int kx = bi % 2, ny = (bi / 2) % 8, z = bi / 16;
    splitT_body(fc1 + (size_t)z * FIN * HD, fc1Th + (size_t)z * HD * FIN,
                fc1Tl + (size_t)z * HD * FIN, FIN, HD, kx * 32, ny * 32, smem);
    return;
  }
  bi -= 80;
  if (bi < 320) {
    int kx = bi % 8, ny = (bi / 8) % 8, z = bi / 64;
    splitT_body(fc2 + (size_t)z * HD * HD, fc2Th + (size_t)z * HD * HD,
                fc2Tl + (size_t)z * HD * HD, HD, HD, kx * 32, ny * 32, smem);
    return;
  }
  bi -= 320;
  if (bi < 32) {
    int kx = bi % 8, ny = bi / 8;
    splitT_body(sW1_1, sW1Th1, sW1Tl1, HD, SH, kx * 32, ny * 32, smem);
    return;
  }
  bi -= 32;
  {
    int kx = bi % 8, ny = bi / 8;
    splitT_body(sW1_2, sW1Th2, sW1Tl2, HD, SH, kx * 32, ny * 32, smem);
  }
}

// ---------------------------------------------------------------------------
// Split-bf16 MFMA GEMM with fused el/er epilogue. A source is either fp32
// (zsrc==null) or the on-the-fly semantic combine sum_m beta[m]*zbh[bn,m,:]
// (zsrc!=null; beta from psum) — this fuses sem_combine into the L2 GEMM.
// Writes bf16 C + el/er from accumulators.
// ---------------------------------------------------------------------------
__global__ __launch_bounds__(256) void gemm_mfma3(
    const float* __restrict__ A, int Mz, size_t aZ,
    const u16* __restrict__ zsrc, const float* __restrict__ psum,
    const int* __restrict__ node_nums,
    const u16* __restrict__ Bh, const u16* __restrict__ Bl, size_t bZ,
    u16* __restrict__ Cbf, size_t cZ,
    int Mrows, int K, int Nc,
    const float* __restrict__ al, const float* __restrict__ ar,
    float* __restrict__ el, float* __restrict__ er) {
  __shared__ u16 sAh[64][40], sAl[64][40], sBh[64][40], sBl[64][40];
  __shared__ float elbuf[64][2], erbuf[64][2];
  int z = blockIdx.z;
  int b = z / Mz, m = z % Mz;
  const float* Ab = A ? (A + (size_t)b * aZ) : nullptr;
  const u16* Bhb = Bh + (size_t)m * bZ;
  const u16* Blb = Bl + (size_t)m * bZ;
  u16* Cfb = Cbf + (size_t)z * cZ;
  int row0 = blockIdx.x * 64, col0 = blockIdx.y * 64;
  int tid = threadIdx.x;
  int arow = tid >> 2, akq = (tid & 3) * 8;
  int wid = tid >> 6, lane = tid & 63;
  int wr = (wid >> 1) * 32, wc = (wid & 1) * 32;
  int lrow = lane & 15, kseg = (lane >> 4) * 8;
  float bbw[M_];
  if (zsrc) beta_from_sums(psum, node_nums, bbw);
  f32x4 zero4 = {0.f, 0.f, 0.f, 0.f};
  f32x4 acc[2][2];
  acc[0][0] = zero4; acc[0][1] = zero4; acc[1][0] = zero4; acc[1][1] = zero4;
  for (int k0 = 0; k0 < K; k0 += 32) {
    float a8[8];
#pragma unroll
    for (int e = 0; e < 8; ++e) a8[e] = 0.f;
    int gr = row0 + arow;
    if (gr < Mrows) {
      if (zsrc) {
        const u16* zr = zsrc + ((size_t)(b * N_ + gr) * M_) * HD + k0 + akq;
#pragma unroll
        for (int mm = 0; mm < M_; ++mm) {
          us8 g = *(const us8*)(zr + mm * HD);
#pragma unroll
          for (int e = 0; e < 8; ++e) a8[e] += bbw[mm] * b2f(g[e]);
        }
      } else {
        const float* ap = Ab + (size_t)gr * K + k0 + akq;
        float4 q0 = *(const float4*)ap;
        float4 q1 = *(const float4*)(ap + 4);
        a8[0] = q0.x; a8[1] = q0.y; a8[2] = q0.z; a8[3] = q0.w;
        a8[4] = q1.x; a8[5] = q1.y; a8[6] = q1.z; a8[7] = q1.w;
      }
    }
    us8 hv, lv;
    {
      u16 th, tl;
#pragma unroll
      for (int e = 0; e < 8; ++e) {
        split2(a8[e], th, tl);
        hv[e] = th; lv[e] = tl;
      }
    }
    *(us8*)&sAh[arow][akq] = hv;
    *(us8*)&sAl[arow][akq] = lv;
    us8 bv = *(const us8*)(Bhb + (size_t)(col0 + arow) * K + k0 + akq);
    us8 blv = *(const us8*)(Blb + (size_t)(col0 + arow) * K + k0 + akq);
    *(us8*)&sBh[arow][akq] = bv;
    *(us8*)&sBl[arow][akq] = blv;
    __syncthreads();
    s16x8 aH[2], aL[2], bH[2], bL[2];
#pragma unroll
    for (int i = 0; i < 2; ++i) {
      aH[i] = *(const s16x8*)&sAh[wr + 16 * i + lrow][kseg];
      aL[i] = *(const s16x8*)&sAl[wr + 16 * i + lrow][kseg];
      bH[i] = *(const s16x8*)&sBh[wc + 16 * i + lrow][kseg];
      bL[i] = *(const s16x8*)&sBl[wc + 16 * i + lrow][kseg];
    }
#pragma unroll
    for (int i = 0; i < 2; ++i)
#pragma unroll
      for (int j = 0; j < 2; ++j) {
        acc[i][j] = __builtin_amdgcn_mfma_f32_16x16x32_bf16(aH[i], bH[j], acc[i][j], 0, 0, 0);
        acc[i][j] = __builtin_amdgcn_mfma_f32_16x16x32_bf16(aH[i], bL[j], acc[i][j], 0, 0, 0);
        acc[i][j] = __builtin_amdgcn_mfma_f32_16x16x32_bf16(aL[i], bH[j], acc[i][j], 0, 0, 0);
      }
    __syncthreads();
  }
#pragma unroll
  for (int i = 0; i < 2; ++i)
#pragma unroll
    for (int j = 0; j < 2; ++j) {
      int ccol = col0 + wc + 16 * j + lrow;
#pragma unroll
      for (int r = 0; r < 4; ++r) {
        int crow = row0 + wr + 16 * i + (lane >> 4) * 4 + r;
        if (crow < Mrows)
          Cfb[(size_t)crow * Nc + ccol] = bf16_bits(acc[i][j][r]);
      }
    }
  // ---- fused el/er epilogue (this block's 64 cols == one head) ----
  float alv0 = al[m * HD + col0 + wc + lrow];
  float alv1 = al[m * HD + col0 + wc + 16 + lrow];
  float arv0 = ar[m * HD + col0 + wc + lrow];
  float arv1 = ar[m * HD + col0 + wc + 16 + lrow];
#pragma unroll
  for (int i = 0; i < 2; ++i)
#pragma unroll
    for (int r = 0; r < 4; ++r) {
      float pl = acc[i][0][r] * alv0 + acc[i][1][r] * alv1;
      float pr = acc[i][0][r] * arv0 + acc[i][1][r] * arv1;
#pragma unroll
      for (int s = 1; s < 16; s <<= 1) {
        pl += __shfl_xor(pl, s, 64);
        pr += __shfl_xor(pr, s, 64);
      }
      if (lrow == 0) {
        int rl = wr + 16 * i + (lane >> 4) * 4 + r;
        elbuf[rl][wc >> 5] = pl;
        erbuf[rl][wc >> 5] = pr;
      }
    }
  __syncthreads();
  if (tid < 64) {
    int grow = row0 + tid;
    if (grow < Mrows) {
      int h = col0 >> 6;
      size_t bmN = (size_t)(b * M_ + m) * N_;
      el[(bmN + grow) * H_ + h] = elbuf[tid][0] + elbuf[tid][1];
      er[(bmN + grow) * H_ + h] = erbuf[tid][0] + erbuf[tid][1];
    }
  }
}

// ---------------------------------------------------------------------------
// GAT aggregation: TWO destinations per wave (same (b,m) slice: d and d+500)
// -> two independent compaction + accumulation chains per wave (2x ILP at
// every latency stall) and half the block count. Barrier-free, direct exp,
// bf16 feat, 4-edge batch per dest, bijective XCD swizzle (2500 blocks).
// ---------------------------------------------------------------------------
__global__ __launch_bounds__(256) void gat_agg(
    const unsigned long long* __restrict__ maskW, const u16* __restrict__ featbf,
    const float* __restrict__ el, const float* __restrict__ er,
    const float* __restrict__ gb, u16* __restrict__ zbh,
    float* __restrict__ psum) {
  int wid = threadIdx.x >> 6, lane = threadIdx.x & 63;
  const int NWG = (B_ * M_ * 500) / 4;  // 2500
  int orig = blockIdx.x;
  if (orig == 0 && threadIdx.x < 8) psum[threadIdx.x] = 0.f;
  // bijective XCD swizzle for nwg=2500 (q=312, r=4)
  int q = NWG >> 3, r = NWG & 7;
  int xcd = orig & 7, ii = orig >> 3;
  int bid = (xcd < r ? xcd * (q + 1) : r * (q + 1) + (xcd - r) * q) + ii;
  int ghw = bid * 4 + wid;        // [0, 10000)
  int bm = ghw / 500;
  int db = ghw % 500;
  int d0 = db, d1 = db + 500;
  int m = bm % M_, b = bm / M_;
  __shared__ u16 slist_all[4][2][1040];
  u16* sl0 = slist_all[wid][0];
  u16* sl1 = slist_all[wid][1];
  if (lane < 4) { sl0[lane] = 0; sl1[lane] = 0; }

  const unsigned long long* mr0 = maskW + ((size_t)bm * N_ + d0) * NW;
  const unsigned long long* mr1 = maskW + ((size_t)bm * N_ + d1) * NW;
  unsigned long long lm = (1ull << lane) - 1ull;
  int c0 = 0, c1 = 0;
#pragma unroll
  for (int qq = 0; qq < NW / 2; ++qq) {
    ulonglong2 wp0 = *(const ulonglong2*)(mr0 + qq * 2);
    ulonglong2 wp1 = *(const ulonglong2*)(mr1 + qq * 2);
    unsigned long long w00 = wp0.x, w01 = wp0.y, w10 = wp1.x, w11 = wp1.y;
    if (w00) {
      if ((w00 >> lane) & 1ull) sl0[c0 + (int)__popcll(w00 & lm)] = (u16)(qq * 128 + lane);
      c0 += (int)__popcll(w00);
    }
    if (w01) {
      if ((w01 >> lane) & 1ull) sl0[c0 + (int)__popcll(w01 & lm)] = (u16)(qq * 128 + 64 + lane);
      c0 += (int)__popcll(w01);
    }
    if (w10) {
      if ((w10 >> lane) & 1ull) sl1[c1 + (int)__popcll(w10 & lm)] = (u16)(qq * 128 + lane);
      c1 += (int)__popcll(w10);
    }
    if (w11) {
      if ((w11 >> lane) & 1ull) sl1[c1 + (int)__popcll(w11 & lm)] = (u16)(qq * 128 + 64 + lane);
      c1 += (int)__popcll(w11);
    }
  }
  int cmax = ((c0 > c1 ? c0 : c1) + 3) & ~3;
  // pad BOTH lists to cmax with a valid index (lists padded -> masked tail
  // iterations load real memory; weights are zeroed by the i+k<c masks)
  u16 p0 = sl0[0], p1 = sl1[0];
  for (int t = c0 + lane; t < cmax; t += 64) sl0[t] = p0;
  for (int t = c1 + lane; t < cmax; t += 64) sl1[t] = p1;

  int h = lane >> 4;
  int lane4 = lane * 4;
  float4 bias4 = *(const float4*)(gb + m * HD + lane4);
  size_t bmN = (size_t)bm * N_;
  float erv0 = er[(bmN + d0) * H_ + h];
  float erv1 = er[(bmN + d1) * H_ + h];
  const float* elb = el + bmN * H_;
  const u16* fbb = featbf + bmN * HD;

  float dA0 = 0.f, dA1 = 0.f, dA2 = 0.f, dA3 = 0.f;
  float dB0 = 0.f, dB1 = 0.f, dB2 = 0.f, dB3 = 0.f;
  f32x4 zz = {0.f, 0.f, 0.f, 0.f};
  f32x4 AA0 = zz, AA1 = zz, AA2 = zz, AA3 = zz;
  f32x4 BB0 = zz, BB1 = zz, BB2 = zz, BB3 = zz;
  for (int i = 0; i < cmax; i += 4) {
    ushort4 sa = *(const ushort4*)&sl0[i];
    ushort4 sb = *(const ushort4*)&sl1[i];
    float ea0 = elb[(size_t)sa.x * H_ + h];
    float ea1 = elb[(size_t)sa.y * H_ + h];
    float ea2 = elb[(size_t)sa.z * H_ + h];
    float ea3 = elb[(size_t)sa.w * H_ + h];
    float eb0 = elb[(size_t)sb.x * H_ + h];
    float eb1 = elb[(size_t)sb.y * H_ + h];
    float eb2 = elb[(size_t)sb.z * H_ + h];
    float eb3 = elb[(size_t)sb.w * H_ + h];
    ushort4 ga0 = *(const ushort4*)(fbb + (size_t)sa.x * HD + lane4);
    ushort4 ga1 = *(const ushort4*)(fbb + (size_t)sa.y * HD + lane4);
    ushort4 ga2 = *(const ushort4*)(fbb + (size_t)sa.z * HD + lane4);
    ushort4 ga3 = *(const ushort4*)(fbb + (size_t)sa.w * HD + lane4);
    ushort4 gb0 = *(const ushort4*)(fbb + (size_t)sb.x * HD + lane4);
    ushort4 gb1 = *(const ushort4*)(fbb + (size_t)sb.y * HD + lane4);
    ushort4 gb2 = *(const ushort4*)(fbb + (size_t)sb.z * HD + lane4);
    ushort4 gb3 = *(const ushort4*)(fbb + (size_t)sb.w * HD + lane4);
    float va0 = ea0 + erv0; va0 = va0 > 0.f ? va0 : 0.2f * va0;
    float va1 = ea1 + erv0; va1 = va1 > 0.f ? va1 : 0.2f * va1;
    float va2 = ea2 + erv0; va2 = va2 > 0.f ? va2 : 0.2f * va2;
    float va3 = ea3 + erv0; va3 = va3 > 0.f ? va3 : 0.2f * va3;
    float vb0 = eb0 + erv1; vb0 = vb0 > 0.f ? vb0 : 0.2f * vb0;
    float vb1 = eb1 + erv1; vb1 = vb1 > 0.f ? vb1 : 0.2f * vb1;
    float vb2 = eb2 + erv1; vb2 = vb2 > 0.f ? vb2 : 0.2f * vb2;
    float vb3 = eb3 + erv1; vb3 = vb3 > 0.f ? vb3 : 0.2f * vb3;
    float wa0 = __expf(va0) * ((i + 0 < c0) ? 1.f : 0.f);
    float wa1 = __expf(va1) * ((i + 1 < c0) ? 1.f : 0.f);
    float wa2 = __expf(va2) * ((i + 2 < c0) ? 1.f : 0.f);
    float wa3 = __expf(va3) * ((i + 3 < c0) ? 1.f : 0.f);
    float wb0 = __expf(vb0) * ((i + 0 < c1) ? 1.f : 0.f);
    float wb1 = __expf(vb1) * ((i + 1 < c1) ? 1.f : 0.f);
    float wb2 = __expf(vb2) * ((i + 2 < c1) ? 1.f : 0.f);
    float wb3 = __expf(vb3) * ((i + 3 < c1) ? 1.f : 0.f);
    f32x4 fa0 = {b2f(ga0.x), b2f(ga0.y), b2f(ga0.z), b2f(ga0.w)};
    f32x4 fa1 = {b2f(ga1.x), b2f(ga1.y), b2f(ga1.z), b2f(ga1.w)};
    f32x4 fa2 = {b2f(ga2.x), b2f(ga2.y), b2f(ga2.z), b2f(ga2.w)};
    f32x4 fa3 = {b2f(ga3.x), b2f(ga3.y), b2f(ga3.z), b2f(ga3.w)};
    f32x4 fb0 = {b2f(gb0.x), b2f(gb0.y), b2f(gb0.z), b2f(gb0.w)};
    f32x4 fb1 = {b2f(gb1.x), b2f(gb1.y), b2f(gb1.z), b2f(gb1.w)};
    f32x4 fb2 = {b2f(gb2.x), b2f(gb2.y), b2f(gb2.z), b2f(gb2.w)};
    f32x4 fb3 = {b2f(gb3.x), b2f(gb3.y), b2f(gb3.z), b2f(gb3.w)};
    dA0 += wa0; dA1 += wa1; dA2 += wa2; dA3 += wa3;
    dB0 += wb0; dB1 += wb1; dB2 += wb2; dB3 += wb3;
    AA0 += wa0 * fa0; AA1 += wa1 * fa1; AA2 += wa2 * fa2; AA3 += wa3 * fa3;
    BB0 += wb0 * fb0; BB1 += wb1 * fb1; BB2 += wb2 * fb2; BB3 += wb3 * fb3;
  }
  float denA = (dA0 + dA1) + (dA2 + dA3);
  float denB = (dB0 + dB1) + (dB2 + dB3);
  f32x4 SA = (AA0 + AA1) + (AA2 + AA3);
  f32x4 SB = (BB0 + BB1) + (BB2 + BB3);
  float invA = (c0 > 0) ? 1.f / denA : 0.f;
  float invB = (c1 > 0) ? 1.f / denB : 0.f;
  // dest d0
  {
    f32x4 o = SA * invA;
    o[0] += bias4.x; o[1] += bias4.y; o[2] += bias4.z; o[3] += bias4.w;
#pragma unroll
    for (int e = 0; e < 4; ++e) o[e] = o[e] > 0.f ? o[e] : (__expf(o[e]) - 1.f);
    ushort4 hh;
    hh.x = bf16_bits(o[0]); hh.y = bf16_bits(o[1]);
    hh.z = bf16_bits(o[2]); hh.w = bf16_bits(o[3]);
    size_t zoff = ((size_t)(b * N_ + d0) * M_ + m) * HD + lane4;
    *(ushort4*)(zbh + zoff) = hh;
  }
  // dest d1
  {
    f32x4 o = SB * invB;
    o[0] += bias4.x; o[1] += bias4.y; o[2] += bias4.z; o[3] += bias4.w;
#pragma unroll
    for (int e = 0; e < 4; ++e) o[e] = o[e] > 0.f ? o[e] : (__expf(o[e]) - 1.f);
    ushort4 hh;
    hh.x = bf16_bits(o[0]); hh.y = bf16_bits(o[1]);
    hh.z = bf16_bits(o[2]); hh.w = bf16_bits(o[3]);
    size_t zoff = ((size_t)(b * N_ + d1) * M_ + m) * HD + lane4;
    *(ushort4*)(zbh + zoff) = hh;
  }
}

// ---------------------------------------------------------------------------
// Semantic GEMM with fused masked per-metapath reduction into psum[5].
// ---------------------------------------------------------------------------
__global__ __launch_bounds__(256) void gemm_sem(
    const u16* __restrict__ Ah, const u16* __restrict__ Bh,
    const float* __restrict__ bias, const float* __restrict__ W2,
    float* __restrict__ psum, const int* __restrict__ node_nums, int Mrows) {
  __shared__ u16 sA[64][40], sB[64][40];
  __shared__ float redm[M_];
  int row0 = blockIdx.x * 64, col0 = blockIdx.y * 64;
  int tid = threadIdx.x;
  int arow = tid >> 2, akq = (tid & 3) * 8;
  int wid = tid >> 6, lane = tid & 63;
  int wr = (wid >> 1) * 32, wc = (wid & 1) * 32;
  int lrow = lane & 15, kseg = (lane >> 4) * 8;
  if (tid < M_) redm[tid] = 0.f;
  f32x4 zero4 = {0.f, 0.f, 0.f, 0.f};
  f32x4 acc[2][2];
  acc[0][0] = zero4; acc[0][1] = zero4; acc[1][0] = zero4; acc[1][1] = zero4;
  for (int k0 = 0; k0 < HD; k0 += 32) {
    us8 av = {0, 0, 0, 0, 0, 0, 0, 0};
    int gr = row0 + arow;
    if (gr < Mrows) av = *(const us8*)(Ah + (size_t)gr * HD + k0 + akq);
    *(us8*)&sA[arow][akq] = av;
    us8 bv = *(const us8*)(Bh + (size_t)(col0 + arow) * HD + k0 + akq);
    *(us8*)&sB[arow][akq] = bv;
    __syncthreads();
    s16x8 aH[2], bH[2];
#pragma unroll
    for (int i = 0; i < 2; ++i) {
      aH[i] = *(const s16x8*)&sA[wr + 16 * i + lrow][kseg];
      bH[i] = *(const s16x8*)&sB[wc + 16 * i + lrow][kseg];
    }
#pragma unroll
    for (int i = 0; i < 2; ++i)
#pragma unroll
      for (int j = 0; j < 2; ++j)
        acc[i][j] = __builtin_amdgcn_mfma_f32_16x16x32_bf16(aH[i], bH[j], acc[i][j], 0, 0, 0);
    __syncthreads();
  }
  int nn0 = node_nums[0], nn1 = node_nums[1], nn2 = node_nums[2], nn3 = node_nums[3];
#pragma unroll
  for (int i = 0; i < 2; ++i) {
#pragma unroll
    for (int r = 0; r < 4; ++r) {
      float part = 0.f;
#pragma unroll
      for (int j = 0; j < 2; ++j) {
        int ccol = col0 + wc + 16 * j + lrow;
        float v = tanhf(acc[i][j][r] + bias[ccol]);
        part += v * W2[ccol];
      }
#pragma unroll
      for (int s = 1; s < 16; s <<= 1) part += __shfl_xor(part, s, 64);
      int crow = row0 + wr + 16 * i + (lane >> 4) * 4 + r;
      if (lrow == 0 && crow < Mrows) {
        int m = crow % M_;
        int bn = crow / M_;
        int bb = bn / N_, n = bn % N_;
        int nn = (bb == 0) ? nn0 : (bb == 1) ? nn1 : (bb == 2) ? nn2 : nn3;
        if (n < nn) atomicAdd(&redm[m], part);
      }
    }
  }
  __syncthreads();
  if (tid < M_) atomicAdd(&psum[tid], redm[tid]);
}

// ---------------------------------------------------------------------------
// Layer-2 combine fused with prediction head: one wave per row. z read bf16.
// ---------------------------------------------------------------------------
__global__ __launch_bounds__(256) void sem_combine_pred(
    const u16* __restrict__ zbh, const float* __restrict__ psum,
    const int* __restrict__ node_nums, const float* __restrict__ W,
    const float* __restrict__ bias, float* __restrict__ out) {
  float bb[M_];
  beta_from_sums(psum, node_nums, bb);
  int row = blockIdx.x * 4 + (threadIdx.x >> 6);
  int lane = threadIdx.x & 63;
  int b = row / N_, n = row % N_;
  const u16* zr = zbh + (size_t)row * M_ * HD + lane * 4;
  float hx = 0.f, hy = 0.f, hz = 0.f, hw = 0.f;
#pragma unroll
  for (int m = 0; m < M_; ++m) {
    ushort4 g = *(const ushort4*)(zr + m * HD);
    hx += bb[m] * b2f(g.x);
    hy += bb[m] * b2f(g.y);
    hz += bb[m] * b2f(g.z);
    hw += bb[m] * b2f(g.w);
  }
  int k = lane * 4;
  float res[OUTD];
#pragma unroll
  for (int o = 0; o < OUTD; ++o) {
    float v = hx * W[(k + 0) * OUTD + o] + hy * W[(k + 1) * OUTD + o] +
              hz * W[(k + 2) * OUTD + o] + hw * W[(k + 3) * OUTD + o];
#pragma unroll
    for (int s = 1; s < 64; s <<= 1) v += __shfl_xor(v, s, 64);
    res[o] = v;
  }
  if (lane == 0) {
    float nm = (n < node_nums[b]) ? 1.f : 0.f;
#pragma unroll
    for (int o = 0; o < OUTD; ++o)
      out[(size_t)row * OUTD + o] = (res[o] + bias[o]) * nm;
  }
}

extern "C" void kernel_launch(void* const* d_in, const int* in_sizes, int n_in,
                              void* d_out, int out_size, void* d_ws, size_t ws_size,
                              hipStream_t stream) {
  const float* x = (const float*)d_in[0];
  const float* adj = (const float*)d_in[1];
  const int* node_nums = (const int*)d_in[2];
  const float* fc1 = (const float*)d_in[3];
  const float* al1 = (const float*)d_in[4];
  const float* ar1 = (const float*)d_in[5];
  const float* gb1 = (const float*)d_in[6];
  const float* sW1_1 = (const float*)d_in[7];
  const float* sb1_1 = (const float*)d_in[8];
  const float* sW2_1 = (const float*)d_in[9];
  const float* fc2 = (const float*)d_in[10];
  const float* al2 = (const float*)d_in[11];
  const float* ar2 = (const float*)d_in[12];
  const float* gb2 = (const float*)d_in[13];
  const float* sW1_2 = (const float*)d_in[14];
  const float* sb1_2 = (const float*)d_in[15];
  const float* sW2_2 = (const float*)d_in[16];
  const float* predW = (const float*)d_in[17];
  const float* predb = (const float*)d_in[18];
  float* out = (float*)d_out;

  char* ws = (char*)d_ws;
  size_t off = 0;
  unsigned long long* maskW = (unsigned long long*)(ws + off);
  off += (size_t)B_ * M_ * N_ * NW * 8;
  u16* featbf = (u16*)(ws + off); off += (size_t)B_ * M_ * N_ * HD * 2;
  float* el = (float*)(ws + off); off += (size_t)B_ * M_ * N_ * H_ * 4;
  float* er = (float*)(ws + off); off += (size_t)B_ * M_ * N_ * H_ * 4;
  u16* zbh = (u16*)(ws + off); off += (size_t)B_ * N_ * M_ * HD * 2;
  float* psum = (float*)(ws + off); off += 64;
  u16* fc1Th = (u16*)(ws + off); off += (size_t)M_ * HD * FIN * 2;
  u16* fc1Tl = (u16*)(ws + off); off += (size_t)M_ * HD * FIN * 2;
  u16* fc2Th = (u16*)(ws + off); off += (size_t)M_ * HD * HD * 2;
  u16* fc2Tl = (u16*)(ws + off); off += (size_t)M_ * HD * HD * 2;
  u16* sW1Th1 = (u16*)(ws + off); off += (size_t)SH * HD * 2;
  u16* sW1Tl1 = (u16*)(ws + off); off += (size_t)SH * HD * 2;
  u16* sW1Th2 = (u16*)(ws + off); off += (size_t)SH * HD * 2;
  u16* sW1Tl2 = (u16*)(ws + off); off += (size_t)SH * HD * 2;

  const int ROWS = B_ * N_ * M_;  // 20000
  const int PREP_BLOCKS = 5120 + 80 + 320 + 32 + 32;  // 5584

  prep_all<<<dim3(PREP_BLOCKS), 256, 0, stream>>>(
      adj, node_nums, maskW, fc1, fc1Th, fc1Tl, fc2, fc2Th, fc2Tl,
      sW1_1, sW1Th1, sW1Tl1, sW1_2, sW1Th2, sW1Tl2);

  // ---- layer 1 ----
  gemm_mfma3<<<dim3(16, HD / 64, B_ * M_), 256, 0, stream>>>(
      x, M_, (size_t)M_ * N_ * FIN, nullptr, nullptr, node_nums,
      fc1Th, fc1Tl, (size_t)HD * FIN,
      featbf, (size_t)N_ * HD, N_, FIN, HD, al1, ar1, el, er);
  gat_agg<<<dim3(ROWS / 8), 256, 0, stream>>>(maskW, featbf, el, er, gb1, zbh, psum);
  gemm_sem<<<dim3((ROWS + 63) / 64, SH / 64), 256, 0, stream>>>(
      zbh, sW1Th1, sb1_1, sW2_1, psum, node_nums, ROWS);

  // ---- layer 2 (A = on-the-fly semantic combine of zbh with beta(psum)) ----
  gemm_mfma3<<<dim3(16, HD / 64, B_ * M_), 256, 0, stream>>>(
      nullptr, M_, 0, zbh, psum, node_nums,
      fc2Th, fc2Tl, (size_t)HD * HD,
      featbf, (size_t)N_ * HD, N_, HD, HD, al2, ar2, el, er);
  gat_agg<<<dim3(ROWS / 8), 256, 0, stream>>>(maskW, featbf, el, er, gb2, zbh, psum);
  gemm_sem<<<dim3((ROWS + 63) / 64, SH / 64), 256, 0, stream>>>(
      zbh, sW1Th2, sb1_2, sW2_2, psum, node_nums, ROWS);
  sem_combine_pred<<<dim3(B_ * N_ / 4), 256, 0, stream>>>(
      zbh, psum, node_nums, predW, predb, out);
}

// Round 15
// 174.568 us; speedup vs baseline: 1.0997x; 1.0997x over previous
//
#include <hip/hip_runtime.h>
#include <hip/hip_bf16.h>

#define B_ 4
#define M_ 5
#define N_ 1000
#define FIN 64
#define H_ 4
#define D_ 64
#define HD 256
#define SH 128
#define OUTD 5
#define NW 16  // u64 words per dest row (1024/64)
#define THRESH_ 0.97f

typedef unsigned short u16;
typedef u16 us8 __attribute__((ext_vector_type(8)));
typedef short s16x8 __attribute__((ext_vector_type(8)));
typedef float f32x4 __attribute__((ext_vector_type(4)));

__device__ inline u16 bf16_bits(float v) {
  __hip_bfloat16 h = __float2bfloat16(v);
  return *reinterpret_cast<u16*>(&h);
}
__device__ inline float bf16_val(u16 b) {
  __hip_bfloat16 h;
  *reinterpret_cast<u16*>(&h) = b;
  return __bfloat162float(h);
}
__device__ inline float b2f(u16 u) {
  union { unsigned int i; float f; } c;
  c.i = ((unsigned int)u) << 16;
  return c.f;
}
__device__ inline void split2(float v, u16& h, u16& l) {
  h = bf16_bits(v);
  l = bf16_bits(v - bf16_val(h));
}
__device__ inline void beta_from_sums(const float* __restrict__ psum,
                                      const int* __restrict__ node_nums,
                                      float* bb) {
  float tot = (float)(node_nums[0] + node_nums[1] + node_nums[2] + node_nums[3]);
  float w[M_], mx = -1e30f;
#pragma unroll
  for (int m = 0; m < M_; ++m) {
    w[m] = psum[m] / tot;
    mx = fmaxf(mx, w[m]);
  }
  float s = 0.f;
#pragma unroll
  for (int m = 0; m < M_; ++m) {
    w[m] = __expf(w[m] - mx);
    s += w[m];
  }
  float inv = 1.f / s;
#pragma unroll
  for (int m = 0; m < M_; ++m) bb[m] = w[m] * inv;
}

// ---------------------------------------------------------------------------
// prep_all: bit-packed transposed edge mask + all weight transpose/split jobs.
// ---------------------------------------------------------------------------
__device__ void splitT_body(const float* __restrict__ s, u16* __restrict__ hiT,
                            u16* __restrict__ loT, int K, int N, int k0, int n0,
                            char* smem) {
  float(*tile)[33] = (float(*)[33])smem;
  int tid = threadIdx.x;
  int kl = tid >> 3, nq = (tid & 7) * 4;
  *(float4*)&tile[kl][nq] = *(const float4*)(s + (size_t)(k0 + kl) * N + n0 + nq);
  __syncthreads();
  int nl = tid >> 3, kq = (tid & 7) * 4;
  ushort4 h, l;
  split2(tile[kq + 0][nl], h.x, l.x);
  split2(tile[kq + 1][nl], h.y, l.y);
  split2(tile[kq + 2][nl], h.z, l.z);
  split2(tile[kq + 3][nl], h.w, l.w);
  size_t o = (size_t)(n0 + nl) * K + k0 + kq;
  *(ushort4*)(hiT + o) = h;
  *(ushort4*)(loT + o) = l;
}

__global__ __launch_bounds__(256) void prep_all(
    const float* __restrict__ adj, const int* __restrict__ node_nums,
    unsigned long long* __restrict__ maskW,
    const float* __restrict__ fc1, u16* __restrict__ fc1Th, u16* __restrict__ fc1Tl,
    const float* __restrict__ fc2, u16* __restrict__ fc2Th, u16* __restrict__ fc2Tl,
    const float* __restrict__ sW1_1, u16* __restrict__ sW1Th1, u16* __restrict__ sW1Tl1,
    const float* __restrict__ sW1_2, u16* __restrict__ sW1Th2, u16* __restrict__ sW1Tl2) {
  __shared__ __align__(16) char smem[4608];
  int bi = blockIdx.x;
  int tid = threadIdx.x;
  if (bi < 5120) {
    int bx = bi & 15, by = (bi >> 4) & 15, bm = bi >> 8;
    int b = bm / M_;
    int s0 = bx * 64, d0 = by * 64;
    int nn = node_nums[b];
    unsigned char(*tile)[65] = (unsigned char(*)[65])smem;
    const float* arow = adj + (size_t)bm * N_ * N_;
#pragma unroll
    for (int k = 0; k < 16; ++k) {
      int idx = k * 256 + tid;
      int sl = idx >> 6, dl = idx & 63;
      int s = s0 + sl, d = d0 + dl;
      unsigned char v = 0;
      if (s < nn && d < nn && s < N_ && d < N_)
        v = (arow[(size_t)s * N_ + d] > THRESH_) ? 1 : 0;
      tile[sl][dl] = v;
    }
    __syncthreads();
    int w = tid >> 6, lane = tid & 63;
#pragma unroll
    for (int j = 0; j < 16; ++j) {
      int dl = w * 16 + j;
      bool act = tile[lane][dl] != 0;
      unsigned long long word = __ballot(act);
      int d = d0 + dl;
      if (lane == 0 && d < N_)
        maskW[((size_t)bm * N_ + d) * NW + bx] = word;
    }
    return;
  }
  bi -= 5120;
  if (bi < 80) {
    int kx = bi % 2, ny = (bi / 2) % 8, z = bi / 16;
    splitT_body(fc1 + (size_t)z * FIN * HD, fc1Th + (size_t)z * HD * FIN,
                fc1Tl + (size_t)z * HD * FIN, FIN, HD, kx * 32, ny * 32, smem);
    return;
  }
  bi -= 80;
  if (bi < 320) {
    int kx = bi % 8, ny = (bi / 8) % 8, z = bi / 64;
    splitT_body(fc2 + (size_t)z * HD * HD, fc2Th + (size_t)z * HD * HD,
                fc2Tl + (size_t)z * HD * HD, HD, HD, kx * 32, ny * 32, smem);
    return;
  }
  bi -= 320;
  if (bi < 32) {
    int kx = bi % 8, ny = bi / 8;
    splitT_body(sW1_1, sW1Th1, sW1Tl1, HD, SH, kx * 32, ny * 32, smem);
    return;
  }
  bi -= 32;
  {
    int kx = bi % 8, ny = bi / 8;
    splitT_body(sW1_2, sW1Th2, sW1Tl2, HD, SH, kx * 32, ny * 32, smem);
  }
}

// ---------------------------------------------------------------------------
// Split-bf16 MFMA GEMM with fused el/er epilogue. A source is either fp32
// (zsrc==null) or the on-the-fly semantic combine sum_m beta[m]*zbh[bn,m,:]
// (zsrc!=null; beta from psum). Writes bf16 C + el/er from accumulators.
// ---------------------------------------------------------------------------
__global__ __launch_bounds__(256) void gemm_mfma3(
    const float* __restrict__ A, int Mz, size_t aZ,
    const u16* __restrict__ zsrc, const float* __restrict__ psum,
    const int* __restrict__ node_nums,
    const u16* __restrict__ Bh, const u16* __restrict__ Bl, size_t bZ,
    u16* __restrict__ Cbf, size_t cZ,
    int Mrows, int K, int Nc,
    const float* __restrict__ al, const float* __restrict__ ar,
    float* __restrict__ el, float* __restrict__ er) {
  __shared__ u16 sAh[64][40], sAl[64][40], sBh[64][40], sBl[64][40];
  __shared__ float elbuf[64][2], erbuf[64][2];
  int z = blockIdx.z;
  int b = z / Mz, m = z % Mz;
  const float* Ab = A ? (A + (size_t)b * aZ) : nullptr;
  const u16* Bhb = Bh + (size_t)m * bZ;
  const u16* Blb = Bl + (size_t)m * bZ;
  u16* Cfb = Cbf + (size_t)z * cZ;
  int row0 = blockIdx.x * 64, col0 = blockIdx.y * 64;
  int tid = threadIdx.x;
  int arow = tid >> 2, akq = (tid & 3) * 8;
  int wid = tid >> 6, lane = tid & 63;
  int wr = (wid >> 1) * 32, wc = (wid & 1) * 32;
  int lrow = lane & 15, kseg = (lane >> 4) * 8;
  float bbw[M_];
  if (zsrc) beta_from_sums(psum, node_nums, bbw);
  f32x4 zero4 = {0.f, 0.f, 0.f, 0.f};
  f32x4 acc[2][2];
  acc[0][0] = zero4; acc[0][1] = zero4; acc[1][0] = zero4; acc[1][1] = zero4;
  for (int k0 = 0; k0 < K; k0 += 32) {
    float a8[8];
#pragma unroll
    for (int e = 0; e < 8; ++e) a8[e] = 0.f;
    int gr = row0 + arow;
    if (gr < Mrows) {
      if (zsrc) {
        const u16* zr = zsrc + ((size_t)(b * N_ + gr) * M_) * HD + k0 + akq;
#pragma unroll
        for (int mm = 0; mm < M_; ++mm) {
          us8 g = *(const us8*)(zr + mm * HD);
#pragma unroll
          for (int e = 0; e < 8; ++e) a8[e] += bbw[mm] * b2f(g[e]);
        }
      } else {
        const float* ap = Ab + (size_t)gr * K + k0 + akq;
        float4 q0 = *(const float4*)ap;
        float4 q1 = *(const float4*)(ap + 4);
        a8[0] = q0.x; a8[1] = q0.y; a8[2] = q0.z; a8[3] = q0.w;
        a8[4] = q1.x; a8[5] = q1.y; a8[6] = q1.z; a8[7] = q1.w;
      }
    }
    us8 hv, lv;
    {
      u16 th, tl;
#pragma unroll
      for (int e = 0; e < 8; ++e) {
        split2(a8[e], th, tl);
        hv[e] = th; lv[e] = tl;
      }
    }
    *(us8*)&sAh[arow][akq] = hv;
    *(us8*)&sAl[arow][akq] = lv;
    us8 bv = *(const us8*)(Bhb + (size_t)(col0 + arow) * K + k0 + akq);
    us8 blv = *(const us8*)(Blb + (size_t)(col0 + arow) * K + k0 + akq);
    *(us8*)&sBh[arow][akq] = bv;
    *(us8*)&sBl[arow][akq] = blv;
    __syncthreads();
    s16x8 aH[2], aL[2], bH[2], bL[2];
#pragma unroll
    for (int i = 0; i < 2; ++i) {
      aH[i] = *(const s16x8*)&sAh[wr + 16 * i + lrow][kseg];
      aL[i] = *(const s16x8*)&sAl[wr + 16 * i + lrow][kseg];
      bH[i] = *(const s16x8*)&sBh[wc + 16 * i + lrow][kseg];
      bL[i] = *(const s16x8*)&sBl[wc + 16 * i + lrow][kseg];
    }
#pragma unroll
    for (int i = 0; i < 2; ++i)
#pragma unroll
      for (int j = 0; j < 2; ++j) {
        acc[i][j] = __builtin_amdgcn_mfma_f32_16x16x32_bf16(aH[i], bH[j], acc[i][j], 0, 0, 0);
        acc[i][j] = __builtin_amdgcn_mfma_f32_16x16x32_bf16(aH[i], bL[j], acc[i][j], 0, 0, 0);
        acc[i][j] = __builtin_amdgcn_mfma_f32_16x16x32_bf16(aL[i], bH[j], acc[i][j], 0, 0, 0);
      }
    __syncthreads();
  }
#pragma unroll
  for (int i = 0; i < 2; ++i)
#pragma unroll
    for (int j = 0; j < 2; ++j) {
      int ccol = col0 + wc + 16 * j + lrow;
#pragma unroll
      for (int r = 0; r < 4; ++r) {
        int crow = row0 + wr + 16 * i + (lane >> 4) * 4 + r;
        if (crow < Mrows)
          Cfb[(size_t)crow * Nc + ccol] = bf16_bits(acc[i][j][r]);
      }
    }
  // ---- fused el/er epilogue (this block's 64 cols == one head) ----
  float alv0 = al[m * HD + col0 + wc + lrow];
  float alv1 = al[m * HD + col0 + wc + 16 + lrow];
  float arv0 = ar[m * HD + col0 + wc + lrow];
  float arv1 = ar[m * HD + col0 + wc + 16 + lrow];
#pragma unroll
  for (int i = 0; i < 2; ++i)
#pragma unroll
    for (int r = 0; r < 4; ++r) {
      float pl = acc[i][0][r] * alv0 + acc[i][1][r] * alv1;
      float pr = acc[i][0][r] * arv0 + acc[i][1][r] * arv1;
#pragma unroll
      for (int s = 1; s < 16; s <<= 1) {
        pl += __shfl_xor(pl, s, 64);
        pr += __shfl_xor(pr, s, 64);
      }
      if (lrow == 0) {
        int rl = wr + 16 * i + (lane >> 4) * 4 + r;
        elbuf[rl][wc >> 5] = pl;
        erbuf[rl][wc >> 5] = pr;
      }
    }
  __syncthreads();
  if (tid < 64) {
    int grow = row0 + tid;
    if (grow < Mrows) {
      int h = col0 >> 6;
      size_t bmN = (size_t)(b * M_ + m) * N_;
      el[(bmN + grow) * H_ + h] = elbuf[tid][0] + elbuf[tid][1];
      er[(bmN + grow) * H_ + h] = erbuf[tid][0] + erbuf[tid][1];
    }
  }
}

// ---------------------------------------------------------------------------
// GAT aggregation (round-13 config: 28 VGPR, 8KB LDS, ~48% occupancy):
// one wave per destination, barrier-free, direct exp, bf16 feat rows,
// ulonglong2 mask reads, 4-edge batched loop, XCD-chunked swizzle.
// Also zeroes psum.
// ---------------------------------------------------------------------------
__global__ __launch_bounds__(256) void gat_agg(
    const unsigned long long* __restrict__ maskW, const u16* __restrict__ featbf,
    const float* __restrict__ el, const float* __restrict__ er,
    const float* __restrict__ gb, u16* __restrict__ zbh,
    float* __restrict__ psum) {
  int wid = threadIdx.x >> 6, lane = threadIdx.x & 63;
  const int NWGQ = (B_ * M_ * N_ / 4) / 8;  // 625
  int orig = blockIdx.x;
  if (orig == 0 && threadIdx.x < 8) psum[threadIdx.x] = 0.f;
  int bid = (orig & 7) * NWGQ + (orig >> 3);  // XCD-chunked, bijective
  int gw = bid * 4 + wid;
  int d = gw % N_, bm = gw / N_;
  int m = bm % M_, b = bm / M_;
  __shared__ u16 slist_all[4][1032];
  u16* slist = slist_all[wid];

  const unsigned long long* mrow = maskW + ((size_t)bm * N_ + d) * NW;
  int cnt = 0;
#pragma unroll
  for (int q = 0; q < NW / 2; ++q) {
    ulonglong2 wp = *(const ulonglong2*)(mrow + q * 2);
    unsigned long long w0 = wp.x, w1 = wp.y;
    if (w0) {
      if ((w0 >> lane) & 1ull) {
        int pos = cnt + (int)__popcll(w0 & ((1ull << lane) - 1ull));
        slist[pos] = (u16)(q * 128 + lane);
      }
      cnt += (int)__popcll(w0);
    }
    if (w1) {
      if ((w1 >> lane) & 1ull) {
        int pos = cnt + (int)__popcll(w1 & ((1ull << lane) - 1ull));
        slist[pos] = (u16)(q * 128 + 64 + lane);
      }
      cnt += (int)__popcll(w1);
    }
  }

  int h = lane >> 4;
  float4 bias4 = *(const float4*)(gb + m * HD + lane * 4);
  size_t zoff = ((size_t)(b * N_ + d) * M_ + m) * HD + lane * 4;
  float4 o;
  if (cnt == 0) {
    o.x = bias4.x > 0.f ? bias4.x : (__expf(bias4.x) - 1.f);
    o.y = bias4.y > 0.f ? bias4.y : (__expf(bias4.y) - 1.f);
    o.z = bias4.z > 0.f ? bias4.z : (__expf(bias4.z) - 1.f);
    o.w = bias4.w > 0.f ? bias4.w : (__expf(bias4.w) - 1.f);
  } else {
    if (lane < 4) slist[cnt + lane] = slist[0];  // pad to safe multiple of 4
    size_t bmN = (size_t)bm * N_;
    float erv = er[(bmN + d) * H_ + h];
    const float* elb = el + bmN * H_;
    const u16* fbb = featbf + bmN * HD;
    int lane4 = lane * 4;
    float den0 = 0.f, den1 = 0.f, den2 = 0.f, den3 = 0.f;
    f32x4 A0 = {0.f, 0.f, 0.f, 0.f}, A1 = A0, A2 = A0, A3 = A0;
    for (int i = 0; i < cnt; i += 4) {
      ushort4 s4 = *(const ushort4*)&slist[i];
      float e0 = elb[(size_t)s4.x * H_ + h];
      float e1 = elb[(size_t)s4.y * H_ + h];
      float e2 = elb[(size_t)s4.z * H_ + h];
      float e3 = elb[(size_t)s4.w * H_ + h];
      ushort4 g0 = *(const ushort4*)(fbb + (size_t)s4.x * HD + lane4);
      ushort4 g1 = *(const ushort4*)(fbb + (size_t)s4.y * HD + lane4);
      ushort4 g2 = *(const ushort4*)(fbb + (size_t)s4.z * HD + lane4);
      ushort4 g3 = *(const ushort4*)(fbb + (size_t)s4.w * HD + lane4);
      float v0 = e0 + erv; v0 = v0 > 0.f ? v0 : 0.2f * v0;
      float v1 = e1 + erv; v1 = v1 > 0.f ? v1 : 0.2f * v1;
      float v2 = e2 + erv; v2 = v2 > 0.f ? v2 : 0.2f * v2;
      float v3 = e3 + erv; v3 = v3 > 0.f ? v3 : 0.2f * v3;
      float w0 = __expf(v0);
      float w1 = __expf(v1) * ((i + 1 < cnt) ? 1.f : 0.f);
      float w2 = __expf(v2) * ((i + 2 < cnt) ? 1.f : 0.f);
      float w3 = __expf(v3) * ((i + 3 < cnt) ? 1.f : 0.f);
      f32x4 f0 = {b2f(g0.x), b2f(g0.y), b2f(g0.z), b2f(g0.w)};
      f32x4 f1 = {b2f(g1.x), b2f(g1.y), b2f(g1.z), b2f(g1.w)};
      f32x4 f2 = {b2f(g2.x), b2f(g2.y), b2f(g2.z), b2f(g2.w)};
      f32x4 f3 = {b2f(g3.x), b2f(g3.y), b2f(g3.z), b2f(g3.w)};
      den0 += w0; den1 += w1; den2 += w2; den3 += w3;
      A0 += w0 * f0; A1 += w1 * f1; A2 += w2 * f2; A3 += w3 * f3;
    }
    float den = (den0 + den1) + (den2 + den3);
    f32x4 A = (A0 + A1) + (A2 + A3);
    float inv = 1.f / den;
    o.x = A[0] * inv + bias4.x;
    o.y = A[1] * inv + bias4.y;
    o.z = A[2] * inv + bias4.z;
    o.w = A[3] * inv + bias4.w;
    o.x = o.x > 0.f ? o.x : (__expf(o.x) - 1.f);
    o.y = o.y > 0.f ? o.y : (__expf(o.y) - 1.f);
    o.z = o.z > 0.f ? o.z : (__expf(o.z) - 1.f);
    o.w = o.w > 0.f ? o.w : (__expf(o.w) - 1.f);
  }
  ushort4 hh;
  hh.x = bf16_bits(o.x);
  hh.y = bf16_bits(o.y);
  hh.z = bf16_bits(o.z);
  hh.w = bf16_bits(o.w);
  *(ushort4*)(zbh + zoff) = hh;
}

// ---------------------------------------------------------------------------
// Semantic GEMM with fused masked per-metapath reduction into psum[5].
// ---------------------------------------------------------------------------
__global__ __launch_bounds__(256) void gemm_sem(
    const u16* __restrict__ Ah, const u16* __restrict__ Bh,
    const float* __restrict__ bias, const float* __restrict__ W2,
    float* __restrict__ psum, const int* __restrict__ node_nums, int Mrows) {
  __shared__ u16 sA[64][40], sB[64][40];
  __shared__ float redm[M_];
  int row0 = blockIdx.x * 64, col0 = blockIdx.y * 64;
  int tid = threadIdx.x;
  int arow = tid >> 2, akq = (tid & 3) * 8;
  int wid = tid >> 6, lane = tid & 63;
  int wr = (wid >> 1) * 32, wc = (wid & 1) * 32;
  int lrow = lane & 15, kseg = (lane >> 4) * 8;
  if (tid < M_) redm[tid] = 0.f;
  f32x4 zero4 = {0.f, 0.f, 0.f, 0.f};
  f32x4 acc[2][2];
  acc[0][0] = zero4; acc[0][1] = zero4; acc[1][0] = zero4; acc[1][1] = zero4;
  for (int k0 = 0; k0 < HD; k0 += 32) {
    us8 av = {0, 0, 0, 0, 0, 0, 0, 0};
    int gr = row0 + arow;
    if (gr < Mrows) av = *(const us8*)(Ah + (size_t)gr * HD + k0 + akq);
    *(us8*)&sA[arow][akq] = av;
    us8 bv = *(const us8*)(Bh + (size_t)(col0 + arow) * HD + k0 + akq);
    *(us8*)&sB[arow][akq] = bv;
    __syncthreads();
    s16x8 aH[2], bH[2];
#pragma unroll
    for (int i = 0; i < 2; ++i) {
      aH[i] = *(const s16x8*)&sA[wr + 16 * i + lrow][kseg];
      bH[i] = *(const s16x8*)&sB[wc + 16 * i + lrow][kseg];
    }
#pragma unroll
    for (int i = 0; i < 2; ++i)
#pragma unroll
      for (int j = 0; j < 2; ++j)
        acc[i][j] = __builtin_amdgcn_mfma_f32_16x16x32_bf16(aH[i], bH[j], acc[i][j], 0, 0, 0);
    __syncthreads();
  }
  int nn0 = node_nums[0], nn1 = node_nums[1], nn2 = node_nums[2], nn3 = node_nums[3];
#pragma unroll
  for (int i = 0; i < 2; ++i) {
#pragma unroll
    for (int r = 0; r < 4; ++r) {
      float part = 0.f;
#pragma unroll
      for (int j = 0; j < 2; ++j) {
        int ccol = col0 + wc + 16 * j + lrow;
        float v = tanhf(acc[i][j][r] + bias[ccol]);
        part += v * W2[ccol];
      }
#pragma unroll
      for (int s = 1; s < 16; s <<= 1) part += __shfl_xor(part, s, 64);
      int crow = row0 + wr + 16 * i + (lane >> 4) * 4 + r;
      if (lrow == 0 && crow < Mrows) {
        int m = crow % M_;
        int bn = crow / M_;
        int bb = bn / N_, n = bn % N_;
        int nn = (bb == 0) ? nn0 : (bb == 1) ? nn1 : (bb == 2) ? nn2 : nn3;
        if (n < nn) atomicAdd(&redm[m], part);
      }
    }
  }
  __syncthreads();
  if (tid < M_) atomicAdd(&psum[tid], redm[tid]);
}

// ---------------------------------------------------------------------------
// Layer-2 combine fused with prediction head: one wave per row. z read bf16.
// ---------------------------------------------------------------------------
__global__ __launch_bounds__(256) void sem_combine_pred(
    const u16* __restrict__ zbh, const float* __restrict__ psum,
    const int* __restrict__ node_nums, const float* __restrict__ W,
    const float* __restrict__ bias, float* __restrict__ out) {
  float bb[M_];
  beta_from_sums(psum, node_nums, bb);
  int row = blockIdx.x * 4 + (threadIdx.x >> 6);
  int lane = threadIdx.x & 63;
  int b = row / N_, n = row % N_;
  const u16* zr = zbh + (size_t)row * M_ * HD + lane * 4;
  float hx = 0.f, hy = 0.f, hz = 0.f, hw = 0.f;
#pragma unroll
  for (int m = 0; m < M_; ++m) {
    ushort4 g = *(const ushort4*)(zr + m * HD);
    hx += bb[m] * b2f(g.x);
    hy += bb[m] * b2f(g.y);
    hz += bb[m] * b2f(g.z);
    hw += bb[m] * b2f(g.w);
  }
  int k = lane * 4;
  float res[OUTD];
#pragma unroll
  for (int o = 0; o < OUTD; ++o) {
    float v = hx * W[(k + 0) * OUTD + o] + hy * W[(k + 1) * OUTD + o] +
              hz * W[(k + 2) * OUTD + o] + hw * W[(k + 3) * OUTD + o];
#pragma unroll
    for (int s = 1; s < 64; s <<= 1) v += __shfl_xor(v, s, 64);
    res[o] = v;
  }
  if (lane == 0) {
    float nm = (n < node_nums[b]) ? 1.f : 0.f;
#pragma unroll
    for (int o = 0; o < OUTD; ++o)
      out[(size_t)row * OUTD + o] = (res[o] + bias[o]) * nm;
  }
}

extern "C" void kernel_launch(void* const* d_in, const int* in_sizes, int n_in,
                              void* d_out, int out_size, void* d_ws, size_t ws_size,
                              hipStream_t stream) {
  const float* x = (const float*)d_in[0];
  const float* adj = (const float*)d_in[1];
  const int* node_nums = (const int*)d_in[2];
  const float* fc1 = (const float*)d_in[3];
  const float* al1 = (const float*)d_in[4];
  const float* ar1 = (const float*)d_in[5];
  const float* gb1 = (const float*)d_in[6];
  const float* sW1_1 = (const float*)d_in[7];
  const float* sb1_1 = (const float*)d_in[8];
  const float* sW2_1 = (const float*)d_in[9];
  const float* fc2 = (const float*)d_in[10];
  const float* al2 = (const float*)d_in[11];
  const float* ar2 = (const float*)d_in[12];
  const float* gb2 = (const float*)d_in[13];
  const float* sW1_2 = (const float*)d_in[14];
  const float* sb1_2 = (const float*)d_in[15];
  const float* sW2_2 = (const float*)d_in[16];
  const float* predW = (const float*)d_in[17];
  const float* predb = (const float*)d_in[18];
  float* out = (float*)d_out;

  char* ws = (char*)d_ws;
  size_t off = 0;
  unsigned long long* maskW = (unsigned long long*)(ws + off);
  off += (size_t)B_ * M_ * N_ * NW * 8;
  u16* featbf = (u16*)(ws + off); off += (size_t)B_ * M_ * N_ * HD * 2;
  float* el = (float*)(ws + off); off += (size_t)B_ * M_ * N_ * H_ * 4;
  float* er = (float*)(ws + off); off += (size_t)B_ * M_ * N_ * H_ * 4;
  u16* zbh = (u16*)(ws + off); off += (size_t)B_ * N_ * M_ * HD * 2;
  float* psum = (float*)(ws + off); off += 64;
  u16* fc1Th = (u16*)(ws + off); off += (size_t)M_ * HD * FIN * 2;
  u16* fc1Tl = (u16*)(ws + off); off += (size_t)M_ * HD * FIN * 2;
  u16* fc2Th = (u16*)(ws + off); off += (size_t)M_ * HD * HD * 2;
  u16* fc2Tl = (u16*)(ws + off); off += (size_t)M_ * HD * HD * 2;
  u16* sW1Th1 = (u16*)(ws + off); off += (size_t)SH * HD * 2;
  u16* sW1Tl1 = (u16*)(ws + off); off += (size_t)SH * HD * 2;
  u16* sW1Th2 = (u16*)(ws + off); off += (size_t)SH * HD * 2;
  u16* sW1Tl2 = (u16*)(ws + off); off += (size_t)SH * HD * 2;

  const int ROWS = B_ * N_ * M_;  // 20000
  const int PREP_BLOCKS = 5120 + 80 + 320 + 32 + 32;  // 5584

  prep_all<<<dim3(PREP_BLOCKS), 256, 0, stream>>>(
      adj, node_nums, maskW, fc1, fc1Th, fc1Tl, fc2, fc2Th, fc2Tl,
      sW1_1, sW1Th1, sW1Tl1, sW1_2, sW1Th2, sW1Tl2);

  // ---- layer 1 ----
  gemm_mfma3<<<dim3(16, HD / 64, B_ * M_), 256, 0, stream>>>(
      x, M_, (size_t)M_ * N_ * FIN, nullptr, nullptr, node_nums,
      fc1Th, fc1Tl, (size_t)HD * FIN,
      featbf, (size_t)N_ * HD, N_, FIN, HD, al1, ar1, el, er);
  gat_agg<<<dim3(ROWS / 4), 256, 0, stream>>>(maskW, featbf, el, er, gb1, zbh, psum);
  gemm_sem<<<dim3((ROWS + 63) / 64, SH / 64), 256, 0, stream>>>(
      zbh, sW1Th1, sb1_1, sW2_1, psum, node_nums, ROWS);

  // ---- layer 2 (A = on-the-fly semantic combine of zbh with beta(psum)) ----
  gemm_mfma3<<<dim3(16, HD / 64, B_ * M_), 256, 0, stream>>>(
      nullptr, M_, 0, zbh, psum, node_nums,
      fc2Th, fc2Tl, (size_t)HD * HD,
      featbf, (size_t)N_ * HD, N_, HD, HD, al2, ar2, el, er);
  gat_agg<<<dim3(ROWS / 4), 256, 0, stream>>>(maskW, featbf, el, er, gb2, zbh, psum);
  gemm_sem<<<dim3((ROWS + 63) / 64, SH / 64), 256, 0, stream>>>(
      zbh, sW1Th2, sb1_2, sW2_2, psum, node_nums, ROWS);
  sem_combine_pred<<<dim3(B_ * N_ / 4), 256, 0, stream>>>(
      zbh, psum, node_nums, predW, predb, out);
}

// Round 16
// 164.518 us; speedup vs baseline: 1.1669x; 1.0611x over previous
//
#include <hip/hip_runtime.h>
#include <hip/hip_bf16.h>

#define B_ 4
#define M_ 5
#define N_ 1000
#define FIN 64
#define H_ 4
#define D_ 64
#define HD 256
#define SH 128
#define OUTD 5
#define NW 16  // u64 words per dest row (1024/64)
#define THRESH_ 0.97f

typedef unsigned short u16;
typedef u16 us8 __attribute__((ext_vector_type(8)));
typedef short s16x8 __attribute__((ext_vector_type(8)));
typedef float f32x4 __attribute__((ext_vector_type(4)));

__device__ inline u16 bf16_bits(float v) {
  __hip_bfloat16 h = __float2bfloat16(v);
  return *reinterpret_cast<u16*>(&h);
}
__device__ inline float bf16_val(u16 b) {
  __hip_bfloat16 h;
  *reinterpret_cast<u16*>(&h) = b;
  return __bfloat162float(h);
}
__device__ inline float b2f(u16 u) {
  union { unsigned int i; float f; } c;
  c.i = ((unsigned int)u) << 16;
  return c.f;
}
__device__ inline void split2(float v, u16& h, u16& l) {
  h = bf16_bits(v);
  l = bf16_bits(v - bf16_val(h));
}
__device__ inline void beta_from_sums(const float* __restrict__ psum,
                                      const int* __restrict__ node_nums,
                                      float* bb) {
  float tot = (float)(node_nums[0] + node_nums[1] + node_nums[2] + node_nums[3]);
  float w[M_], mx = -1e30f;
#pragma unroll
  for (int m = 0; m < M_; ++m) {
    w[m] = psum[m] / tot;
    mx = fmaxf(mx, w[m]);
  }
  float s = 0.f;
#pragma unroll
  for (int m = 0; m < M_; ++m) {
    w[m] = __expf(w[m] - mx);
    s += w[m];
  }
  float inv = 1.f / s;
#pragma unroll
  for (int m = 0; m < M_; ++m) bb[m] = w[m] * inv;
}

// ---------------------------------------------------------------------------
// prep_all: bit-packed transposed edge mask + all weight transpose/split jobs.
// ---------------------------------------------------------------------------
__device__ void splitT_body(const float* __restrict__ s, u16* __restrict__ hiT,
                            u16* __restrict__ loT, int K, int N, int k0, int n0,
                            char* smem) {
  float(*tile)[33] = (float(*)[33])smem;
  int tid = threadIdx.x;
  int kl = tid >> 3, nq = (tid & 7) * 4;
  *(float4*)&tile[kl][nq] = *(const float4*)(s + (size_t)(k0 + kl) * N + n0 + nq);
  __syncthreads();
  int nl = tid >> 3, kq = (tid & 7) * 4;
  ushort4 h, l;
  split2(tile[kq + 0][nl], h.x, l.x);
  split2(tile[kq + 1][nl], h.y, l.y);
  split2(tile[kq + 2][nl], h.z, l.z);
  split2(tile[kq + 3][nl], h.w, l.w);
  size_t o = (size_t)(n0 + nl) * K + k0 + kq;
  *(ushort4*)(hiT + o) = h;
  *(ushort4*)(loT + o) = l;
}

__global__ __launch_bounds__(256) void prep_all(
    const float* __restrict__ adj, const int* __restrict__ node_nums,
    unsigned long long* __restrict__ maskW,
    const float* __restrict__ fc1, u16* __restrict__ fc1Th, u16* __restrict__ fc1Tl,
    const float* __restrict__ fc2, u16* __restrict__ fc2Th, u16* __restrict__ fc2Tl,
    const float* __restrict__ sW1_1, u16* __restrict__ sW1Th1, u16* __restrict__ sW1Tl1,
    const float* __restrict__ sW1_2, u16* __restrict__ sW1Th2, u16* __restrict__ sW1Tl2) {
  __shared__ __align__(16) char smem[4608];
  int bi = blockIdx.x;
  int tid = threadIdx.x;
  if (bi < 5120) {
    int bx = bi & 15, by = (bi >> 4) & 15, bm = bi >> 8;
    int b = bm / M_;
    int s0 = bx * 64, d0 = by * 64;
    int nn = node_nums[b];
    unsigned char(*tile)[65] = (unsigned char(*)[65])smem;
    const float* arow = adj + (size_t)bm * N_ * N_;
#pragma unroll
    for (int k = 0; k < 16; ++k) {
      int idx = k * 256 + tid;
      int sl = idx >> 6, dl = idx & 63;
      int s = s0 + sl, d = d0 + dl;
      unsigned char v = 0;
      if (s < nn && d < nn && s < N_ && d < N_)
        v = (arow[(size_t)s * N_ + d] > THRESH_) ? 1 : 0;
      tile[sl][dl] = v;
    }
    __syncthreads();
    int w = tid >> 6, lane = tid & 63;
#pragma unroll
    for (int j = 0; j < 16; ++j) {
      int dl = w * 16 + j;
      bool act = tile[lane][dl] != 0;
      unsigned long long word = __ballot(act);
      int d = d0 + dl;
      if (lane == 0 && d < N_)
        maskW[((size_t)bm * N_ + d) * NW + bx] = word;
    }
    return;
  }
  bi -= 5120;
  if (bi < 80) {
    int kx = bi % 2, ny = (bi / 2) % 8, z = bi / 16;
    splitT_body(fc1 + (size_t)z * FIN * HD, fc1Th + (size_t)z * HD * FIN,
                fc1Tl + (size_t)z * HD * FIN, FIN, HD, kx * 32, ny * 32, smem);
    return;
  }
  bi -= 80;
  if (bi < 320) {
    int kx = bi % 8, ny = (bi / 8) % 8, z = bi / 64;
    splitT_body(fc2 + (size_t)z * HD * HD, fc2Th + (size_t)z * HD * HD,
                fc2Tl + (size_t)z * HD * HD, HD, HD, kx * 32, ny * 32, smem);
    return;
  }
  bi -= 320;
  if (bi < 32) {
    int kx = bi % 8, ny = bi / 8;
    splitT_body(sW1_1, sW1Th1, sW1Tl1, HD, SH, kx * 32, ny * 32, smem);
    return;
  }
  bi -= 32;
  {
    int kx = bi % 8, ny = bi / 8;
    splitT_body(sW1_2, sW1Th2, sW1Tl2, HD, SH, kx * 32, ny * 32, smem);
  }
}

// ---------------------------------------------------------------------------
// Split-bf16 MFMA GEMM (feat) with FUSED el/er epilogue.
// A fp32 (in-register hi/lo split), B pre-transposed hi/lo, 3 mfma/product.
// Writes bf16 feat + el/er from accumulators.
// ---------------------------------------------------------------------------
__global__ __launch_bounds__(256) void gemm_mfma3(
    const float* __restrict__ A, int Mz, size_t aZ,
    const u16* __restrict__ Bh, const u16* __restrict__ Bl, size_t bZ,
    u16* __restrict__ Cbf, size_t cZ,
    int Mrows, int K, int Nc,
    const float* __restrict__ al, const float* __restrict__ ar,
    float* __restrict__ el, float* __restrict__ er) {
  __shared__ u16 sAh[64][40], sAl[64][40], sBh[64][40], sBl[64][40];
  __shared__ float elbuf[64][2], erbuf[64][2];
  int z = blockIdx.z;
  int b = z / Mz, m = z % Mz;
  const float* Ab = A + (size_t)b * aZ;
  const u16* Bhb = Bh + (size_t)m * bZ;
  const u16* Blb = Bl + (size_t)m * bZ;
  u16* Cfb = Cbf + (size_t)z * cZ;
  int row0 = blockIdx.x * 64, col0 = blockIdx.y * 64;
  int tid = threadIdx.x;
  int arow = tid >> 2, akq = (tid & 3) * 8;
  int wid = tid >> 6, lane = tid & 63;
  int wr = (wid >> 1) * 32, wc = (wid & 1) * 32;
  int lrow = lane & 15, kseg = (lane >> 4) * 8;
  f32x4 zero4 = {0.f, 0.f, 0.f, 0.f};
  f32x4 acc[2][2];
  acc[0][0] = zero4; acc[0][1] = zero4; acc[1][0] = zero4; acc[1][1] = zero4;
  for (int k0 = 0; k0 < K; k0 += 32) {
    float4 a0 = make_float4(0.f, 0.f, 0.f, 0.f), a1 = a0;
    int gr = row0 + arow;
    if (gr < Mrows) {
      const float* ap = Ab + (size_t)gr * K + k0 + akq;
      a0 = *(const float4*)ap;
      a1 = *(const float4*)(ap + 4);
    }
    us8 hv, lv;
    {
      u16 th, tl;
      split2(a0.x, th, tl); hv[0] = th; lv[0] = tl;
      split2(a0.y, th, tl); hv[1] = th; lv[1] = tl;
      split2(a0.z, th, tl); hv[2] = th; lv[2] = tl;
      split2(a0.w, th, tl); hv[3] = th; lv[3] = tl;
      split2(a1.x, th, tl); hv[4] = th; lv[4] = tl;
      split2(a1.y, th, tl); hv[5] = th; lv[5] = tl;
      split2(a1.z, th, tl); hv[6] = th; lv[6] = tl;
      split2(a1.w, th, tl); hv[7] = th; lv[7] = tl;
    }
    *(us8*)&sAh[arow][akq] = hv;
    *(us8*)&sAl[arow][akq] = lv;
    us8 bv = *(const us8*)(Bhb + (size_t)(col0 + arow) * K + k0 + akq);
    us8 blv = *(const us8*)(Blb + (size_t)(col0 + arow) * K + k0 + akq);
    *(us8*)&sBh[arow][akq] = bv;
    *(us8*)&sBl[arow][akq] = blv;
    __syncthreads();
    s16x8 aH[2], aL[2], bH[2], bL[2];
#pragma unroll
    for (int i = 0; i < 2; ++i) {
      aH[i] = *(const s16x8*)&sAh[wr + 16 * i + lrow][kseg];
      aL[i] = *(const s16x8*)&sAl[wr + 16 * i + lrow][kseg];
      bH[i] = *(const s16x8*)&sBh[wc + 16 * i + lrow][kseg];
      bL[i] = *(const s16x8*)&sBl[wc + 16 * i + lrow][kseg];
    }
#pragma unroll
    for (int i = 0; i < 2; ++i)
#pragma unroll
      for (int j = 0; j < 2; ++j) {
        acc[i][j] = __builtin_amdgcn_mfma_f32_16x16x32_bf16(aH[i], bH[j], acc[i][j], 0, 0, 0);
        acc[i][j] = __builtin_amdgcn_mfma_f32_16x16x32_bf16(aH[i], bL[j], acc[i][j], 0, 0, 0);
        acc[i][j] = __builtin_amdgcn_mfma_f32_16x16x32_bf16(aL[i], bH[j], acc[i][j], 0, 0, 0);
      }
    __syncthreads();
  }
  // ---- C write (bf16 only) ----
#pragma unroll
  for (int i = 0; i < 2; ++i)
#pragma unroll
    for (int j = 0; j < 2; ++j) {
      int ccol = col0 + wc + 16 * j + lrow;
#pragma unroll
      for (int r = 0; r < 4; ++r) {
        int crow = row0 + wr + 16 * i + (lane >> 4) * 4 + r;
        if (crow < Mrows)
          Cfb[(size_t)crow * Nc + ccol] = bf16_bits(acc[i][j][r]);
      }
    }
  // ---- fused el/er epilogue (this block's 64 cols == one head) ----
  float alv0 = al[m * HD + col0 + wc + lrow];
  float alv1 = al[m * HD + col0 + wc + 16 + lrow];
  float arv0 = ar[m * HD + col0 + wc + lrow];
  float arv1 = ar[m * HD + col0 + wc + 16 + lrow];
#pragma unroll
  for (int i = 0; i < 2; ++i)
#pragma unroll
    for (int r = 0; r < 4; ++r) {
      float pl = acc[i][0][r] * alv0 + acc[i][1][r] * alv1;
      float pr = acc[i][0][r] * arv0 + acc[i][1][r] * arv1;
#pragma unroll
      for (int s = 1; s < 16; s <<= 1) {
        pl += __shfl_xor(pl, s, 64);
        pr += __shfl_xor(pr, s, 64);
      }
      if (lrow == 0) {
        int rl = wr + 16 * i + (lane >> 4) * 4 + r;
        elbuf[rl][wc >> 5] = pl;
        erbuf[rl][wc >> 5] = pr;
      }
    }
  __syncthreads();
  if (tid < 64) {
    int grow = row0 + tid;
    if (grow < Mrows) {
      int h = col0 >> 6;
      size_t bmN = (size_t)(b * M_ + m) * N_;
      el[(bmN + grow) * H_ + h] = elbuf[tid][0] + elbuf[tid][1];
      er[(bmN + grow) * H_ + h] = erbuf[tid][0] + erbuf[tid][1];
    }
  }
}

// ---------------------------------------------------------------------------
// GAT aggregation: one wave per destination, barrier-free, direct exp,
// bf16 feat rows, ulonglong2 mask reads, 4-edge batched loop, XCD swizzle.
// Also zeroes psum. (28 VGPR / 8 KB LDS config.)
// ---------------------------------------------------------------------------
__global__ __launch_bounds__(256) void gat_agg(
    const unsigned long long* __restrict__ maskW, const u16* __restrict__ featbf,
    const float* __restrict__ el, const float* __restrict__ er,
    const float* __restrict__ gb, u16* __restrict__ zbh,
    float* __restrict__ psum) {
  int wid = threadIdx.x >> 6, lane = threadIdx.x & 63;
  const int NWGQ = (B_ * M_ * N_ / 4) / 8;  // 625
  int orig = blockIdx.x;
  if (orig == 0 && threadIdx.x < 8) psum[threadIdx.x] = 0.f;
  int bid = (orig & 7) * NWGQ + (orig >> 3);  // XCD-chunked, bijective
  int gw = bid * 4 + wid;
  int d = gw % N_, bm = gw / N_;
  int m = bm % M_, b = bm / M_;
  __shared__ u16 slist_all[4][1032];
  u16* slist = slist_all[wid];

  const unsigned long long* mrow = maskW + ((size_t)bm * N_ + d) * NW;
  int cnt = 0;
#pragma unroll
  for (int q = 0; q < NW / 2; ++q) {
    ulonglong2 wp = *(const ulonglong2*)(mrow + q * 2);
    unsigned long long w0 = wp.x, w1 = wp.y;
    if (w0) {
      if ((w0 >> lane) & 1ull) {
        int pos = cnt + (int)__popcll(w0 & ((1ull << lane) - 1ull));
        slist[pos] = (u16)(q * 128 + lane);
      }
      cnt += (int)__popcll(w0);
    }
    if (w1) {
      if ((w1 >> lane) & 1ull) {
        int pos = cnt + (int)__popcll(w1 & ((1ull << lane) - 1ull));
        slist[pos] = (u16)(q * 128 + 64 + lane);
      }
      cnt += (int)__popcll(w1);
    }
  }

  int h = lane >> 4;
  float4 bias4 = *(const float4*)(gb + m * HD + lane * 4);
  size_t zoff = ((size_t)(b * N_ + d) * M_ + m) * HD + lane * 4;
  float4 o;
  if (cnt == 0) {
    o.x = bias4.x > 0.f ? bias4.x : (__expf(bias4.x) - 1.f);
    o.y = bias4.y > 0.f ? bias4.y : (__expf(bias4.y) - 1.f);
    o.z = bias4.z > 0.f ? bias4.z : (__expf(bias4.z) - 1.f);
    o.w = bias4.w > 0.f ? bias4.w : (__expf(bias4.w) - 1.f);
  } else {
    if (lane < 4) slist[cnt + lane] = slist[0];  // pad to safe multiple of 4
    size_t bmN = (size_t)bm * N_;
    float erv = er[(bmN + d) * H_ + h];
    const float* elb = el + bmN * H_;
    const u16* fbb = featbf + bmN * HD;
    int lane4 = lane * 4;
    float den0 = 0.f, den1 = 0.f, den2 = 0.f, den3 = 0.f;
    f32x4 A0 = {0.f, 0.f, 0.f, 0.f}, A1 = A0, A2 = A0, A3 = A0;
    for (int i = 0; i < cnt; i += 4) {
      ushort4 s4 = *(const ushort4*)&slist[i];
      float e0 = elb[(size_t)s4.x * H_ + h];
      float e1 = elb[(size_t)s4.y * H_ + h];
      float e2 = elb[(size_t)s4.z * H_ + h];
      float e3 = elb[(size_t)s4.w * H_ + h];
      ushort4 g0 = *(const ushort4*)(fbb + (size_t)s4.x * HD + lane4);
      ushort4 g1 = *(const ushort4*)(fbb + (size_t)s4.y * HD + lane4);
      ushort4 g2 = *(const ushort4*)(fbb + (size_t)s4.z * HD + lane4);
      ushort4 g3 = *(const ushort4*)(fbb + (size_t)s4.w * HD + lane4);
      float v0 = e0 + erv; v0 = v0 > 0.f ? v0 : 0.2f * v0;
      float v1 = e1 + erv; v1 = v1 > 0.f ? v1 : 0.2f * v1;
      float v2 = e2 + erv; v2 = v2 > 0.f ? v2 : 0.2f * v2;
      float v3 = e3 + erv; v3 = v3 > 0.f ? v3 : 0.2f * v3;
      float w0 = __expf(v0);
      float w1 = __expf(v1) * ((i + 1 < cnt) ? 1.f : 0.f);
      float w2 = __expf(v2) * ((i + 2 < cnt) ? 1.f : 0.f);
      float w3 = __expf(v3) * ((i + 3 < cnt) ? 1.f : 0.f);
      f32x4 f0 = {b2f(g0.x), b2f(g0.y), b2f(g0.z), b2f(g0.w)};
      f32x4 f1 = {b2f(g1.x), b2f(g1.y), b2f(g1.z), b2f(g1.w)};
      f32x4 f2 = {b2f(g2.x), b2f(g2.y), b2f(g2.z), b2f(g2.w)};
      f32x4 f3 = {b2f(g3.x), b2f(g3.y), b2f(g3.z), b2f(g3.w)};
      den0 += w0; den1 += w1; den2 += w2; den3 += w3;
      A0 += w0 * f0; A1 += w1 * f1; A2 += w2 * f2; A3 += w3 * f3;
    }
    float den = (den0 + den1) + (den2 + den3);
    f32x4 A = (A0 + A1) + (A2 + A3);
    float inv = 1.f / den;
    o.x = A[0] * inv + bias4.x;
    o.y = A[1] * inv + bias4.y;
    o.z = A[2] * inv + bias4.z;
    o.w = A[3] * inv + bias4.w;
    o.x = o.x > 0.f ? o.x : (__expf(o.x) - 1.f);
    o.y = o.y > 0.f ? o.y : (__expf(o.y) - 1.f);
    o.z = o.z > 0.f ? o.z : (__expf(o.z) - 1.f);
    o.w = o.w > 0.f ? o.w : (__expf(o.w) - 1.f);
  }
  ushort4 hh;
  hh.x = bf16_bits(o.x);
  hh.y = bf16_bits(o.y);
  hh.z = bf16_bits(o.z);
  hh.w = bf16_bits(o.w);
  *(ushort4*)(zbh + zoff) = hh;
}

// ---------------------------------------------------------------------------
// Semantic GEMM with fused masked per-metapath reduction into psum[5].
// ---------------------------------------------------------------------------
__global__ __launch_bounds__(256) void gemm_sem(
    const u16* __restrict__ Ah, const u16* __restrict__ Bh,
    const float* __restrict__ bias, const float* __restrict__ W2,
    float* __restrict__ psum, const int* __restrict__ node_nums, int Mrows) {
  __shared__ u16 sA[64][40], sB[64][40];
  __shared__ float redm[M_];
  int row0 = blockIdx.x * 64, col0 = blockIdx.y * 64;
  int tid = threadIdx.x;
  int arow = tid >> 2, akq = (tid & 3) * 8;
  int wid = tid >> 6, lane = tid & 63;
  int wr = (wid >> 1) * 32, wc = (wid & 1) * 32;
  int lrow = lane & 15, kseg = (lane >> 4) * 8;
  if (tid < M_) redm[tid] = 0.f;
  f32x4 zero4 = {0.f, 0.f, 0.f, 0.f};
  f32x4 acc[2][2];
  acc[0][0] = zero4; acc[0][1] = zero4; acc[1][0] = zero4; acc[1][1] = zero4;
  for (int k0 = 0; k0 < HD; k0 += 32) {
    us8 av = {0, 0, 0, 0, 0, 0, 0, 0};
    int gr = row0 + arow;
    if (gr < Mrows) av = *(const us8*)(Ah + (size_t)gr * HD + k0 + akq);
    *(us8*)&sA[arow][akq] = av;
    us8 bv = *(const us8*)(Bh + (size_t)(col0 + arow) * HD + k0 + akq);
    *(us8*)&sB[arow][akq] = bv;
    __syncthreads();
    s16x8 aH[2], bH[2];
#pragma unroll
    for (int i = 0; i < 2; ++i) {
      aH[i] = *(const s16x8*)&sA[wr + 16 * i + lrow][kseg];
      bH[i] = *(const s16x8*)&sB[wc + 16 * i + lrow][kseg];
    }
#pragma unroll
    for (int i = 0; i < 2; ++i)
#pragma unroll
      for (int j = 0; j < 2; ++j)
        acc[i][j] = __builtin_amdgcn_mfma_f32_16x16x32_bf16(aH[i], bH[j], acc[i][j], 0, 0, 0);
    __syncthreads();
  }
  int nn0 = node_nums[0], nn1 = node_nums[1], nn2 = node_nums[2], nn3 = node_nums[3];
#pragma unroll
  for (int i = 0; i < 2; ++i) {
#pragma unroll
    for (int r = 0; r < 4; ++r) {
      float part = 0.f;
#pragma unroll
      for (int j = 0; j < 2; ++j) {
        int ccol = col0 + wc + 16 * j + lrow;
        float v = tanhf(acc[i][j][r] + bias[ccol]);
        part += v * W2[ccol];
      }
#pragma unroll
      for (int s = 1; s < 16; s <<= 1) part += __shfl_xor(part, s, 64);
      int crow = row0 + wr + 16 * i + (lane >> 4) * 4 + r;
      if (lrow == 0 && crow < Mrows) {
        int m = crow % M_;
        int bn = crow / M_;
        int bb = bn / N_, n = bn % N_;
        int nn = (bb == 0) ? nn0 : (bb == 1) ? nn1 : (bb == 2) ? nn2 : nn3;
        if (n < nn) atomicAdd(&redm[m], part);
      }
    }
  }
  __syncthreads();
  if (tid < M_) atomicAdd(&psum[tid], redm[tid]);
}

// ---------------------------------------------------------------------------
// h[b,n,hd] = sum_m beta[m] * z[b,n,m,hd]; z read bf16, h written fp32.
// ---------------------------------------------------------------------------
__global__ __launch_bounds__(256) void sem_combine(const u16* __restrict__ zbh,
                                                   const float* __restrict__ psum,
                                                   const int* __restrict__ node_nums,
                                                   float* __restrict__ hout) {
  float bb[M_];
  beta_from_sums(psum, node_nums, bb);
  int q = blockIdx.x * 256 + threadIdx.x;  // over B*N*HD/4
  int hd4 = (q & 63) * 4;
  int bn = q >> 6;
  const u16* zr = zbh + (size_t)bn * M_ * HD + hd4;
  f32x4 acc = {0.f, 0.f, 0.f, 0.f};
#pragma unroll
  for (int m = 0; m < M_; ++m) {
    ushort4 g = *(const ushort4*)(zr + m * HD);
    f32x4 f = {b2f(g.x), b2f(g.y), b2f(g.z), b2f(g.w)};
    acc += bb[m] * f;
  }
  *(f32x4*)(hout + (size_t)bn * HD + hd4) = acc;
}

// ---------------------------------------------------------------------------
// Layer-2 combine fused with prediction head: one wave per row. z read bf16.
// ---------------------------------------------------------------------------
__global__ __launch_bounds__(256) void sem_combine_pred(
    const u16* __restrict__ zbh, const float* __restrict__ psum,
    const int* __restrict__ node_nums, const float* __restrict__ W,
    const float* __restrict__ bias, float* __restrict__ out) {
  float bb[M_];
  beta_from_sums(psum, node_nums, bb);
  int row = blockIdx.x * 4 + (threadIdx.x >> 6);
  int lane = threadIdx.x & 63;
  int b = row / N_, n = row % N_;
  const u16* zr = zbh + (size_t)row * M_ * HD + lane * 4;
  float hx = 0.f, hy = 0.f, hz = 0.f, hw = 0.f;
#pragma unroll
  for (int m = 0; m < M_; ++m) {
    ushort4 g = *(const ushort4*)(zr + m * HD);
    hx += bb[m] * b2f(g.x);
    hy += bb[m] * b2f(g.y);
    hz += bb[m] * b2f(g.z);
    hw += bb[m] * b2f(g.w);
  }
  int k = lane * 4;
  float res[OUTD];
#pragma unroll
  for (int o = 0; o < OUTD; ++o) {
    float v = hx * W[(k + 0) * OUTD + o] + hy * W[(k + 1) * OUTD + o] +
              hz * W[(k + 2) * OUTD + o] + hw * W[(k + 3) * OUTD + o];
#pragma unroll
    for (int s = 1; s < 64; s <<= 1) v += __shfl_xor(v, s, 64);
    res[o] = v;
  }
  if (lane == 0) {
    float nm = (n < node_nums[b]) ? 1.f : 0.f;
#pragma unroll
    for (int o = 0; o < OUTD; ++o)
      out[(size_t)row * OUTD + o] = (res[o] + bias[o]) * nm;
  }
}

extern "C" void kernel_launch(void* const* d_in, const int* in_sizes, int n_in,
                              void* d_out, int out_size, void* d_ws, size_t ws_size,
                              hipStream_t stream) {
  const float* x = (const float*)d_in[0];
  const float* adj = (const float*)d_in[1];
  const int* node_nums = (const int*)d_in[2];
  const float* fc1 = (const float*)d_in[3];
  const float* al1 = (const float*)d_in[4];
  const float* ar1 = (const float*)d_in[5];
  const float* gb1 = (const float*)d_in[6];
  const float* sW1_1 = (const float*)d_in[7];
  const float* sb1_1 = (const float*)d_in[8];
  const float* sW2_1 = (const float*)d_in[9];
  const float* fc2 = (const float*)d_in[10];
  const float* al2 = (const float*)d_in[11];
  const float* ar2 = (const float*)d_in[12];
  const float* gb2 = (const float*)d_in[13];
  const float* sW1_2 = (const float*)d_in[14];
  const float* sb1_2 = (const float*)d_in[15];
  const float* sW2_2 = (const float*)d_in[16];
  const float* predW = (const float*)d_in[17];
  const float* predb = (const float*)d_in[18];
  float* out = (float*)d_out;

  char* ws = (char*)d_ws;
  size_t off = 0;
  unsigned long long* maskW = (unsigned long long*)(ws + off);
  off += (size_t)B_ * M_ * N_ * NW * 8;
  u16* featbf = (u16*)(ws + off); off += (size_t)B_ * M_ * N_ * HD * 2;
  float* el = (float*)(ws + off); off += (size_t)B_ * M_ * N_ * H_ * 4;
  float* er = (float*)(ws + off); off += (size_t)B_ * M_ * N_ * H_ * 4;
  u16* zbh = (u16*)(ws + off); off += (size_t)B_ * N_ * M_ * HD * 2;
  float* h1 = (float*)(ws + off); off += (size_t)B_ * N_ * HD * 4;
  float* psum = (float*)(ws + off); off += 64;
  u16* fc1Th = (u16*)(ws + off); off += (size_t)M_ * HD * FIN * 2;
  u16* fc1Tl = (u16*)(ws + off); off += (size_t)M_ * HD * FIN * 2;
  u16* fc2Th = (u16*)(ws + off); off += (size_t)M_ * HD * HD * 2;
  u16* fc2Tl = (u16*)(ws + off); off += (size_t)M_ * HD * HD * 2;
  u16* sW1Th1 = (u16*)(ws + off); off += (size_t)SH * HD * 2;
  u16* sW1Tl1 = (u16*)(ws + off); off += (size_t)SH * HD * 2;
  u16* sW1Th2 = (u16*)(ws + off); off += (size_t)SH * HD * 2;
  u16* sW1Tl2 = (u16*)(ws + off); off += (size_t)SH * HD * 2;

  const int ROWS = B_ * N_ * M_;  // 20000
  const int PREP_BLOCKS = 5120 + 80 + 320 + 32 + 32;  // 5584

  prep_all<<<dim3(PREP_BLOCKS), 256, 0, stream>>>(
      adj, node_nums, maskW, fc1, fc1Th, fc1Tl, fc2, fc2Th, fc2Tl,
      sW1_1, sW1Th1, sW1Tl1, sW1_2, sW1Th2, sW1Tl2);

  // ---- layer 1 ----
  gemm_mfma3<<<dim3(16, HD / 64, B_ * M_), 256, 0, stream>>>(
      x, M_, (size_t)M_ * N_ * FIN, fc1Th, fc1Tl, (size_t)HD * FIN,
      featbf, (size_t)N_ * HD, N_, FIN, HD, al1, ar1, el, er);
  gat_agg<<<dim3(ROWS / 4), 256, 0, stream>>>(maskW, featbf, el, er, gb1, zbh, psum);
  gemm_sem<<<dim3((ROWS + 63) / 64, SH / 64), 256, 0, stream>>>(
      zbh, sW1Th1, sb1_1, sW2_1, psum, node_nums, ROWS);
  sem_combine<<<dim3(B_ * N_ * HD / 1024), 256, 0, stream>>>(zbh, psum, node_nums, h1);

  // ---- layer 2 ----
  gemm_mfma3<<<dim3(16, HD / 64, B_ * M_), 256, 0, stream>>>(
      h1, M_, (size_t)N_ * HD, fc2Th, fc2Tl, (size_t)HD * HD,
      featbf, (size_t)N_ * HD, N_, HD, HD, al2, ar2, el, er);
  gat_agg<<<dim3(ROWS / 4), 256, 0, stream>>>(maskW, featbf, el, er, gb2, zbh, psum);
  gemm_sem<<<dim3((ROWS + 63) / 64, SH / 64), 256, 0, stream>>>(
      zbh, sW1Th2, sb1_2, sW2_2, psum, node_nums, ROWS);
  sem_combine_pred<<<dim3(B_ * N_ / 4), 256, 0, stream>>>(
      zbh, psum, node_nums, predW, predb, out);
}